// Round 11
// baseline (2974.429 us; speedup 1.0000x reference)
//
#include <hip/hip_runtime.h>
#include <hip/hip_bf16.h>

#define N_NODES 100000
#define N_EDGES 1600000
#define DIM     128
#define N_LAYERS 7
#define N_GRAPHS 64
#define SNN_IN  512
#define SNN_HID 1024
#define NCLS    10
#define M_PAD   100096   // 782 * 128
#define MBLK    782
#define NBK     782      // buckets of 128 nodes
#define SORT_CHUNK 4096
#define SORT_NCH   391   // ceil(1600000/4096)
#define XPAIRS  (N_NODES * 64)
#define WELEMS  (N_LAYERS * DIM * 256)
#define AGG_BLOCKS 2048
#define AGG_WPS    ((AGG_BLOCKS / 8) * 4)   // waves per slice = 1024

typedef __attribute__((ext_vector_type(8))) short short8;
typedef __attribute__((ext_vector_type(4))) float f32x4;

__device__ __forceinline__ unsigned int f2bf(float f) {
    unsigned int u = __float_as_uint(f);
    return (u + 0x7fffu + ((u >> 16) & 1u)) >> 16;   // RNE
}
__device__ __forceinline__ float bf2f(unsigned short b) {
    return __uint_as_float(((unsigned int)b) << 16);
}
__device__ __forceinline__ void acc_pair(unsigned int u, float& lo, float& hi) {
    lo += __uint_as_float(u << 16);
    hi += __uint_as_float(u & 0xffff0000u);
}

// ---- setup: fp32 x -> bf16 h0 in SLICE-MAJOR layout hs[slice][node][16 dims],
// and W -> Wt[l][n][k] bf16 ----
__global__ void k_convert(const float* __restrict__ x, const float* __restrict__ wrel,
                          const float* __restrict__ wroot, unsigned int* __restrict__ h,
                          unsigned short* __restrict__ Wt) {
    int i = blockIdx.x * blockDim.x + threadIdx.x;
    if (i < XPAIRS) {
        int node = i >> 6, rem = i & 63, d = rem >> 3, j = rem & 7;
        float2 v = ((const float2*)x)[node * 64 + d * 8 + j];
        h[((size_t)d * M_PAD + node) * 8 + j] = f2bf(v.x) | (f2bf(v.y) << 16);
    } else {
        int idx = i - XPAIRS;
        if (idx < WELEMS) {
            int l = idx >> 15, rem = idx & 32767, n = rem >> 8, k = rem & 255;
            float v = (k < 128) ? wrel[l * 16384 + k * 128 + n]
                                : wroot[l * 16384 + (k - 128) * 128 + n];
            Wt[idx] = (unsigned short)f2bf(v);
        }
    }
}

// ---- sort pass A1: per-chunk LDS histogram over 782 buckets (no global atomics) ----
__global__ __launch_bounds__(256) void k_histA(const int* __restrict__ dst,
                                               int* __restrict__ chunk_hist) {
    __shared__ int hist[NBK];
    int b = blockIdx.x, t = threadIdx.x;
    int e0 = b * SORT_CHUNK;
    int e1 = e0 + SORT_CHUNK; if (e1 > N_EDGES) e1 = N_EDGES;
    for (int i = t; i < NBK; i += 256) hist[i] = 0;
    __syncthreads();
    for (int e = e0 + t; e < e1; e += 256) atomicAdd(&hist[dst[e] >> 7], 1);
    __syncthreads();
    for (int i = t; i < NBK; i += 256) chunk_hist[b * NBK + i] = hist[i];
}

// ---- sort pass A2: per-bucket exclusive prefix over the 391 chunk counts ----
__global__ __launch_bounds__(64) void k_colscan(int* __restrict__ chunk_hist,
                                                int* __restrict__ btot) {
    int b = blockIdx.x;
    int lane = threadIdx.x;
    const int C = (SORT_NCH + 63) / 64;   // 7
    int vals[C]; int sum = 0;
    #pragma unroll
    for (int j = 0; j < C; j++) {
        int c = lane * C + j;
        vals[j] = (c < SORT_NCH) ? chunk_hist[c * NBK + b] : 0;
        sum += vals[j];
    }
    int s = sum;
    #pragma unroll
    for (int o = 1; o < 64; o <<= 1) { int t = __shfl_up(s, o); if (lane >= o) s += t; }
    if (lane == 63) btot[b] = s;
    int run = s - sum;
    #pragma unroll
    for (int j = 0; j < C; j++) {
        int c = lane * C + j;
        if (c < SORT_NCH) chunk_hist[c * NBK + b] = run;
        run += vals[j];
    }
}

// ---- tiny cross-bucket scan ----
__global__ __launch_bounds__(256) void k_bscan(const int* __restrict__ btot,
                                               int* __restrict__ bucket_base) {
    __shared__ int wsum[4];
    int tid = threadIdx.x, lane = tid & 63, wid = tid >> 6;
    int i0 = tid * 4;
    int v[4]; int sum = 0;
    #pragma unroll
    for (int j = 0; j < 4; j++) { int i = i0 + j; v[j] = (i < NBK) ? btot[i] : 0; sum += v[j]; }
    int s = sum;
    #pragma unroll
    for (int o = 1; o < 64; o <<= 1) { int t = __shfl_up(s, o); if (lane >= o) s += t; }
    if (lane == 63) wsum[wid] = s;
    __syncthreads();
    if (tid == 0) {
        int acc = 0;
        #pragma unroll
        for (int w = 0; w < 4; w++) { acc += wsum[w]; wsum[w] = acc; }
    }
    __syncthreads();
    int prefix = s - sum + (wid ? wsum[wid - 1] : 0);
    #pragma unroll
    for (int j = 0; j < 4; j++) { int i = i0 + j; if (i < NBK) bucket_base[i] = prefix; prefix += v[j]; }
}

// ---- sort pass A3: scatter via LDS cursors ----
__global__ __launch_bounds__(256) void k_scatterA(const int* __restrict__ src,
                                                  const int* __restrict__ dst,
                                                  const int* __restrict__ chunk_hist,
                                                  const int* __restrict__ bucket_base,
                                                  unsigned int* __restrict__ pairs) {
    __shared__ int lcur[NBK];
    int b = blockIdx.x, t = threadIdx.x;
    int e0 = b * SORT_CHUNK;
    int e1 = e0 + SORT_CHUNK; if (e1 > N_EDGES) e1 = N_EDGES;
    for (int i = t; i < NBK; i += 256) lcur[i] = chunk_hist[b * NBK + i] + bucket_base[i];
    __syncthreads();
    for (int e = e0 + t; e < e1; e += 256) {
        int d = dst[e];
        int bk = d >> 7;
        int pos = atomicAdd(&lcur[bk], 1);
        pairs[pos] = (unsigned int)src[e] | ((unsigned int)(d & 127) << 17);
    }
}

// ---- pass B: per bucket, derive per-node offsets locally; writes row_off ----
__global__ __launch_bounds__(256) void k_bucketB(const unsigned int* __restrict__ pairs,
                                                 const int* __restrict__ bucket_base,
                                                 const int* __restrict__ btot,
                                                 int* __restrict__ row_off,
                                                 int* __restrict__ sorted_src) {
    __shared__ int lcnt[128];
    __shared__ int loff[128];
    int b = blockIdx.x, t = threadIdx.x;
    int node0 = b << 7;
    int nn = N_NODES - node0; if (nn > 128) nn = 128;
    int base = bucket_base[b];
    int end  = base + btot[b];
    if (t < 128) lcnt[t] = 0;
    __syncthreads();
    for (int i = base + t; i < end; i += 256) atomicAdd(&lcnt[pairs[i] >> 17], 1);
    __syncthreads();
    if (t < 64) {
        int v0 = lcnt[2 * t], v1 = lcnt[2 * t + 1];
        int s = v0 + v1, ps = s;
        #pragma unroll
        for (int o = 1; o < 64; o <<= 1) { int u = __shfl_up(ps, o); if (t >= o) ps += u; }
        int excl = ps - s;
        loff[2 * t] = excl; loff[2 * t + 1] = excl + v0;
    }
    __syncthreads();
    if (t < nn) row_off[node0 + t] = base + loff[t];
    if (b == NBK - 1 && t == 0) row_off[N_NODES] = end;
    if (t < 128) lcnt[t] = 0;
    __syncthreads();
    for (int i = base + t; i < end; i += 256) {
        unsigned int p = pairs[i];
        int l = p >> 17;
        int pos = atomicAdd(&lcnt[l], 1);
        sorted_src[base + loff[l] + pos] = (int)(p & 0x1FFFFu);
    }
}

// ---- aggregation: slice-partitioned. Block handles slice d = blockIdx&7; with
// round-robin blockIdx->XCD dispatch each XCD gathers from ONE 3.2MB slice that
// fits its 4MiB L2 (vs 25.6MB table -> 45% miss before). 32 lane-pairs per wave:
// 32 edges per load instruction; persistent waves over nodes. ----
__global__ __launch_bounds__(256) void k_agg(const uint4* __restrict__ h4,
                                             const int* __restrict__ row_off,
                                             const int* __restrict__ sorted_src,
                                             uint4* __restrict__ agg4) {
    int d = blockIdx.x & 7;
    int w = (blockIdx.x >> 3) * 4 + (threadIdx.x >> 6);   // wave id within slice
    int lane = threadIdx.x & 63;
    int p = lane >> 1, half = lane & 1;
    const uint4* hs = h4 + (size_t)d * (M_PAD * 2);
    uint4* as = agg4 + (size_t)d * (M_PAD * 2);
    for (int node = w; node < N_NODES; node += AGG_WPS) {
        int beg = row_off[node], end = row_off[node + 1];
        float a[8] = {0.f, 0.f, 0.f, 0.f, 0.f, 0.f, 0.f, 0.f};
        for (int base = beg; base < end; base += 32) {
            int e = base + p;
            bool val = e < end;
            int sidx = val ? sorted_src[e] : 0;
            uint4 r = val ? hs[(size_t)sidx * 2 + half] : make_uint4(0u, 0u, 0u, 0u);
            acc_pair(r.x, a[0], a[1]); acc_pair(r.y, a[2], a[3]);
            acc_pair(r.z, a[4], a[5]); acc_pair(r.w, a[6], a[7]);
        }
        // reduce across the 32 pairs (xor offsets keep bit0=half intact)
        #pragma unroll
        for (int i = 0; i < 8; i++) {
            a[i] += __shfl_xor(a[i], 2);
            a[i] += __shfl_xor(a[i], 4);
            a[i] += __shfl_xor(a[i], 8);
            a[i] += __shfl_xor(a[i], 16);
            a[i] += __shfl_xor(a[i], 32);
        }
        if (p == 0) {
            uint4 o;
            o.x = f2bf(a[0]) | (f2bf(a[1]) << 16);
            o.y = f2bf(a[2]) | (f2bf(a[3]) << 16);
            o.z = f2bf(a[4]) | (f2bf(a[5]) << 16);
            o.w = f2bf(a[6]) | (f2bf(a[7]) << 16);
            as[(size_t)node * 2 + half] = o;
        }
    }
}

// ---- fused GraphConv GEMM, LDS-free K-loop, 128-row tiles (R9-proven), with
// slice-major A addressing. A-fragment needs dims [ksub..ksub+8) contiguous —
// available inside a 16-dim slice. Epilogue stores slice-major (2KB runs). ----
__global__ __launch_bounds__(256) void k_gemm(const unsigned short* __restrict__ Ag,
                                              const unsigned short* __restrict__ H,
                                              const unsigned short* __restrict__ Wt,
                                              const float* __restrict__ bias,
                                              unsigned short* __restrict__ Hout) {
    __shared__ unsigned short Es[64 * 144];  // 18.4 KB epilogue staging only
    int tid = threadIdx.x;
    int lane = tid & 63, wid = tid >> 6;
    int wr = (wid >> 1) * 64, wc = (wid & 1) * 64;
    int row0 = blockIdx.x * 128;
    f32x4 acc[4][4] = {};

    int ksub = (lane >> 4) * 8;
    int m0 = row0 + wr + (lane & 15);
    const unsigned short* Bb = Wt + (size_t)(wc + (lane & 15)) * 256 + ksub;

    auto load_frags = [&](short8* a, short8* b, int s) {
        const unsigned short* basep = (s < 4) ? Ag : H;
        int dim = (s & 3) * 32 + ksub;
        const unsigned short* ap = basep + ((size_t)(dim >> 4) * M_PAD + m0) * 16 + (dim & 15);
        #pragma unroll
        for (int mi = 0; mi < 4; mi++) a[mi] = *(const short8*)(ap + mi * 16 * 16);
        const unsigned short* bp = Bb + s * 32;
        #pragma unroll
        for (int ni = 0; ni < 4; ni++) b[ni] = *(const short8*)(bp + ni * 16 * 256);
    };
    auto do_mfma = [&](short8* a, short8* b) {
        #pragma unroll
        for (int mi = 0; mi < 4; mi++)
            #pragma unroll
            for (int ni = 0; ni < 4; ni++)
                acc[mi][ni] = __builtin_amdgcn_mfma_f32_16x16x32_bf16(a[mi], b[ni], acc[mi][ni], 0, 0, 0);
    };

    short8 a0[4], b0[4], a1[4], b1[4];
    load_frags(a0, b0, 0);
    #pragma unroll
    for (int s = 0; s < 8; s += 2) {
        load_frags(a1, b1, s + 1);
        do_mfma(a0, b0);
        if (s + 2 < 8) load_frags(a0, b0, s + 2);
        do_mfma(a1, b1);
    }

    // epilogue: C/D map col=lane&15, row=(lane>>4)*4+reg (m89-verified)
    int cb = wc + (lane & 15);
    int rs = (lane >> 4) * 4;
    #pragma unroll
    for (int p = 0; p < 2; ++p) {
        __syncthreads();
        if (wr == 64 * p) {
            #pragma unroll
            for (int ni = 0; ni < 4; ni++) {
                int col = cb + ni * 16;
                float bn = bias[col];
                #pragma unroll
                for (int mi = 0; mi < 4; mi++) {
                    int rloc = mi * 16 + rs;
                    #pragma unroll
                    for (int rr = 0; rr < 4; rr++) {
                        float v = acc[mi][ni][rr] + bn;
                        v = v > 0.f ? v : 0.f;
                        Es[(rloc + rr) * 144 + col] = (unsigned short)f2bf(v);
                    }
                }
            }
        }
        __syncthreads();
        // slice-major stores: per slice dd, 64 nodes x 32B = 2KB contiguous
        #pragma unroll
        for (int j = 0; j < 4; j++) {
            int c = j * 256 + tid;            // 0..1023
            int dd = c >> 7, rem = c & 127, node = rem >> 1, hf = rem & 1;
            uint4* gd = (uint4*)Hout + (size_t)dd * (M_PAD * 2)
                        + (size_t)(row0 + 64 * p + node) * 2 + hf;
            *gd = *(const uint4*)(Es + node * 144 + dd * 16 + hf * 8);
        }
    }
}

// ---- pooling: batch is sorted; slice-major h addressing ----
__global__ __launch_bounds__(128) void k_pool(const unsigned short* __restrict__ h,
                                              const int* __restrict__ batch,
                                              float* __restrict__ pooled, int* __restrict__ counts) {
    __shared__ int bsh[128];
    int start = blockIdx.x * 128, t = threadIdx.x;
    int end = start + 128; if (end > N_NODES) end = N_NODES;
    int nn = end - start;
    if (t < nn) bsh[t] = batch[start + t];
    __syncthreads();
    const unsigned short* hd = h + (size_t)(t >> 4) * M_PAD * 16 + (t & 15);
    float acc = 0.f; int cur = -1, cnt = 0;
    for (int i = 0; i < nn; i++) {
        int g = bsh[i];
        if (g != cur) {
            if (cur >= 0) { atomicAdd(&pooled[cur * 128 + t], acc); if (t == 0) atomicAdd(&counts[cur], cnt); }
            cur = g; acc = 0.f; cnt = 0;
        }
        acc += bf2f(hd[(size_t)(start + i) * 16]);
        cnt++;
    }
    if (cur >= 0) { atomicAdd(&pooled[cur * 128 + t], acc); if (t == 0) atomicAdd(&counts[cur], cnt); }
}

// ---- SNN layer 1: snn_h = relu(x @ w1 + b1), fp32 vector ----
__global__ __launch_bounds__(256) void k_snn1(const float* __restrict__ x, const float* __restrict__ w1,
                                              const float* __restrict__ b1, float* __restrict__ out) {
    __shared__ float xs[SNN_IN];
    int m = blockIdx.x, tid = threadIdx.x;
    for (int i = tid; i < SNN_IN; i += 256) xs[i] = x[m * SNN_IN + i];
    __syncthreads();
    float a0 = 0.f, a1 = 0.f, a2 = 0.f, a3 = 0.f;
    for (int k = 0; k < SNN_IN; k++) {
        float xv = xs[k];
        const float* wr = w1 + (size_t)k * SNN_HID + tid;
        a0 += xv * wr[0]; a1 += xv * wr[256]; a2 += xv * wr[512]; a3 += xv * wr[768];
    }
    float v;
    v = a0 + b1[tid];       out[m * SNN_HID + tid]       = v > 0.f ? v : 0.f;
    v = a1 + b1[tid + 256]; out[m * SNN_HID + tid + 256] = v > 0.f ? v : 0.f;
    v = a2 + b1[tid + 512]; out[m * SNN_HID + tid + 512] = v > 0.f ? v : 0.f;
    v = a3 + b1[tid + 768]; out[m * SNN_HID + tid + 768] = v > 0.f ? v : 0.f;
}

// ---- head: gnn logits + snn logits + fusion, one wave per graph ----
__global__ __launch_bounds__(64) void k_head(const float* __restrict__ pooled, const int* __restrict__ counts,
                                             const float* __restrict__ lin_w, const float* __restrict__ lin_b,
                                             const float* __restrict__ snn_h, const float* __restrict__ w2,
                                             const float* __restrict__ b2, const float* __restrict__ fuse_w,
                                             const float* __restrict__ fuse_b, float* __restrict__ out) {
    int m = blockIdx.x, lane = threadIdx.x;
    __shared__ float sm[20];
    float cnt = (float)(counts[m] > 0 ? counts[m] : 1);
    float p0 = pooled[m * 128 + lane] / cnt;
    float p1 = pooled[m * 128 + 64 + lane] / cnt;
    for (int c = 0; c < NCLS; c++) {
        float v = p0 * lin_w[lane * 10 + c] + p1 * lin_w[(lane + 64) * 10 + c];
        #pragma unroll
        for (int o = 32; o > 0; o >>= 1) v += __shfl_down(v, o);
        if (lane == 0) sm[10 + c] = v + lin_b[c];
    }
    for (int c = 0; c < NCLS; c++) {
        float v = 0.f;
        #pragma unroll
        for (int j = 0; j < 16; j++) {
            int k = lane + j * 64;
            v += snn_h[m * SNN_HID + k] * w2[k * 10 + c];
        }
        #pragma unroll
        for (int o = 32; o > 0; o >>= 1) v += __shfl_down(v, o);
        if (lane == 0) sm[c] = 0.85f * (v + b2[c]);
    }
    __syncthreads();
    if (lane < NCLS) {
        float o = fuse_b[lane];
        #pragma unroll
        for (int j = 0; j < 20; j++) o += sm[j] * fuse_w[j * 10 + lane];
        out[m * 10 + lane] = o;
    }
}

extern "C" void kernel_launch(void* const* d_in, const int* in_sizes, int n_in,
                              void* d_out, int out_size, void* d_ws, size_t ws_size,
                              hipStream_t stream) {
    const float* snn_x  = (const float*)d_in[0];
    const float* x      = (const float*)d_in[1];
    const int*   ei     = (const int*)d_in[2];
    const int*   batch  = (const int*)d_in[3];
    const float* w1     = (const float*)d_in[4];
    const float* b1     = (const float*)d_in[5];
    const float* w2     = (const float*)d_in[6];
    const float* b2     = (const float*)d_in[7];
    const float* wrel   = (const float*)d_in[8];
    const float* wroot  = (const float*)d_in[9];
    const float* brel   = (const float*)d_in[10];
    const float* lin_w  = (const float*)d_in[11];
    const float* lin_b  = (const float*)d_in[12];
    const float* fuse_w = (const float*)d_in[13];
    const float* fuse_b = (const float*)d_in[14];
    const int* srcv = ei;
    const int* dstv = ei + N_EDGES;

    char* ws = (char*)d_ws;
    size_t off = 0;
    auto alloc = [&](size_t b) { char* p = ws + off; off = (off + b + 255) & ~(size_t)255; return p; };
    unsigned short* h0   = (unsigned short*)alloc((size_t)M_PAD * 128 * 2);   // 25.6 MB
    unsigned short* h1   = (unsigned short*)alloc((size_t)M_PAD * 128 * 2);   // 25.6 MB
    unsigned short* agg  = (unsigned short*)alloc((size_t)M_PAD * 128 * 2);   // 25.6 MB
    unsigned short* Wt   = (unsigned short*)alloc((size_t)N_LAYERS * 128 * 256 * 2);
    int* sorted_src = (int*)alloc((size_t)N_EDGES * 4);
    unsigned int* pairs = (unsigned int*)alloc((size_t)N_EDGES * 4);
    int* chunk_hist = (int*)alloc((size_t)SORT_NCH * NBK * 4);   // 1.22 MB
    int* row_off    = (int*)alloc((size_t)(N_NODES + 1) * 4);
    int* btot       = (int*)alloc((size_t)NBK * 4);
    int* bucket_base= (int*)alloc((size_t)NBK * 4);
    float* pooled   = (float*)alloc((size_t)N_GRAPHS * 128 * 4);
    int* counts     = (int*)alloc((size_t)N_GRAPHS * 4);
    float* snn_h    = (float*)alloc((size_t)N_GRAPHS * SNN_HID * 4);

    hipMemsetAsync(pooled, 0, (size_t)N_GRAPHS * 128 * 4, stream);
    hipMemsetAsync(counts, 0, (size_t)N_GRAPHS * 4, stream);

    k_histA<<<SORT_NCH, 256, 0, stream>>>(dstv, chunk_hist);
    k_colscan<<<NBK, 64, 0, stream>>>(chunk_hist, btot);
    k_bscan<<<1, 256, 0, stream>>>(btot, bucket_base);
    k_scatterA<<<SORT_NCH, 256, 0, stream>>>(srcv, dstv, chunk_hist, bucket_base, pairs);
    k_bucketB<<<NBK, 256, 0, stream>>>(pairs, bucket_base, btot, row_off, sorted_src);
    k_convert<<<(XPAIRS + WELEMS + 255) / 256, 256, 0, stream>>>(x, wrel, wroot, (unsigned int*)h0, Wt);

    unsigned short* hc = h0;
    unsigned short* hn = h1;
    for (int l = 0; l < N_LAYERS; l++) {
        k_agg<<<AGG_BLOCKS, 256, 0, stream>>>((const uint4*)hc, row_off, sorted_src, (uint4*)agg);
        k_gemm<<<MBLK, 256, 0, stream>>>(agg, hc, Wt + (size_t)l * 128 * 256, brel + l * 128, hn);
        unsigned short* t = hc; hc = hn; hn = t;
    }
    k_pool<<<(N_NODES + 127) / 128, 128, 0, stream>>>(hc, batch, pooled, counts);
    k_snn1<<<N_GRAPHS, 256, 0, stream>>>(snn_x, w1, b1, snn_h);
    k_head<<<N_GRAPHS, 64, 0, stream>>>(pooled, counts, lin_w, lin_b, snn_h, w2, b2, fuse_w, fuse_b,
                                        (float*)d_out);
}

// Round 12
// 1031.448 us; speedup vs baseline: 2.8837x; 2.8837x over previous
//
#include <hip/hip_runtime.h>
#include <hip/hip_bf16.h>

#define N_NODES 100000
#define N_EDGES 1600000
#define DIM     128
#define N_LAYERS 7
#define N_GRAPHS 64
#define SNN_IN  512
#define SNN_HID 1024
#define NCLS    10
#define M_PAD   100096   // 782 * 128
#define MBLK    782
#define NBK     782      // buckets of 128 nodes
#define SORT_CHUNK 4096
#define SORT_NCH   391   // ceil(1600000/4096)
#define XPAIRS  (N_NODES * 64)
#define WELEMS  (N_LAYERS * DIM * 256)
#define AGG_BLOCKS 2048
#define AGG_WAVES  (AGG_BLOCKS * 4)

typedef __attribute__((ext_vector_type(8))) short short8;
typedef __attribute__((ext_vector_type(4))) float f32x4;

__device__ __forceinline__ unsigned int f2bf(float f) {
    unsigned int u = __float_as_uint(f);
    return (u + 0x7fffu + ((u >> 16) & 1u)) >> 16;   // RNE
}
__device__ __forceinline__ float bf2f(unsigned short b) {
    return __uint_as_float(((unsigned int)b) << 16);
}
__device__ __forceinline__ void acc_pair(unsigned int u, float& lo, float& hi) {
    lo += __uint_as_float(u << 16);
    hi += __uint_as_float(u & 0xffff0000u);
}

// ---- setup: fp32 x -> bf16 h0 pairs (node-major), W -> Wt[l][n][k] bf16 ----
__global__ void k_convert(const float* __restrict__ x, const float* __restrict__ wrel,
                          const float* __restrict__ wroot, unsigned int* __restrict__ h,
                          unsigned short* __restrict__ Wt) {
    int i = blockIdx.x * blockDim.x + threadIdx.x;
    if (i < XPAIRS) {
        float2 v = ((const float2*)x)[i];
        h[i] = f2bf(v.x) | (f2bf(v.y) << 16);
    } else {
        int idx = i - XPAIRS;
        if (idx < WELEMS) {
            int l = idx >> 15, rem = idx & 32767, n = rem >> 8, k = rem & 255;
            float v = (k < 128) ? wrel[l * 16384 + k * 128 + n]
                                : wroot[l * 16384 + (k - 128) * 128 + n];
            Wt[idx] = (unsigned short)f2bf(v);
        }
    }
}

// ---- sort pass A1: per-chunk LDS histogram over 782 buckets (no global atomics) ----
__global__ __launch_bounds__(256) void k_histA(const int* __restrict__ dst,
                                               int* __restrict__ chunk_hist) {
    __shared__ int hist[NBK];
    int b = blockIdx.x, t = threadIdx.x;
    int e0 = b * SORT_CHUNK;
    int e1 = e0 + SORT_CHUNK; if (e1 > N_EDGES) e1 = N_EDGES;
    for (int i = t; i < NBK; i += 256) hist[i] = 0;
    __syncthreads();
    for (int e = e0 + t; e < e1; e += 256) atomicAdd(&hist[dst[e] >> 7], 1);
    __syncthreads();
    for (int i = t; i < NBK; i += 256) chunk_hist[b * NBK + i] = hist[i];
}

// ---- sort pass A2: per-bucket exclusive prefix over the 391 chunk counts ----
__global__ __launch_bounds__(64) void k_colscan(int* __restrict__ chunk_hist,
                                                int* __restrict__ btot) {
    int b = blockIdx.x;
    int lane = threadIdx.x;
    const int C = (SORT_NCH + 63) / 64;   // 7
    int vals[C]; int sum = 0;
    #pragma unroll
    for (int j = 0; j < C; j++) {
        int c = lane * C + j;
        vals[j] = (c < SORT_NCH) ? chunk_hist[c * NBK + b] : 0;
        sum += vals[j];
    }
    int s = sum;
    #pragma unroll
    for (int o = 1; o < 64; o <<= 1) { int t = __shfl_up(s, o); if (lane >= o) s += t; }
    if (lane == 63) btot[b] = s;
    int run = s - sum;
    #pragma unroll
    for (int j = 0; j < C; j++) {
        int c = lane * C + j;
        if (c < SORT_NCH) chunk_hist[c * NBK + b] = run;
        run += vals[j];
    }
}

// ---- tiny cross-bucket scan ----
__global__ __launch_bounds__(256) void k_bscan(const int* __restrict__ btot,
                                               int* __restrict__ bucket_base) {
    __shared__ int wsum[4];
    int tid = threadIdx.x, lane = tid & 63, wid = tid >> 6;
    int i0 = tid * 4;
    int v[4]; int sum = 0;
    #pragma unroll
    for (int j = 0; j < 4; j++) { int i = i0 + j; v[j] = (i < NBK) ? btot[i] : 0; sum += v[j]; }
    int s = sum;
    #pragma unroll
    for (int o = 1; o < 64; o <<= 1) { int t = __shfl_up(s, o); if (lane >= o) s += t; }
    if (lane == 63) wsum[wid] = s;
    __syncthreads();
    if (tid == 0) {
        int acc = 0;
        #pragma unroll
        for (int w = 0; w < 4; w++) { acc += wsum[w]; wsum[w] = acc; }
    }
    __syncthreads();
    int prefix = s - sum + (wid ? wsum[wid - 1] : 0);
    #pragma unroll
    for (int j = 0; j < 4; j++) { int i = i0 + j; if (i < NBK) bucket_base[i] = prefix; prefix += v[j]; }
}

// ---- sort pass A3: scatter via LDS cursors ----
__global__ __launch_bounds__(256) void k_scatterA(const int* __restrict__ src,
                                                  const int* __restrict__ dst,
                                                  const int* __restrict__ chunk_hist,
                                                  const int* __restrict__ bucket_base,
                                                  unsigned int* __restrict__ pairs) {
    __shared__ int lcur[NBK];
    int b = blockIdx.x, t = threadIdx.x;
    int e0 = b * SORT_CHUNK;
    int e1 = e0 + SORT_CHUNK; if (e1 > N_EDGES) e1 = N_EDGES;
    for (int i = t; i < NBK; i += 256) lcur[i] = chunk_hist[b * NBK + i] + bucket_base[i];
    __syncthreads();
    for (int e = e0 + t; e < e1; e += 256) {
        int d = dst[e];
        int bk = d >> 7;
        int pos = atomicAdd(&lcur[bk], 1);
        pairs[pos] = (unsigned int)src[e] | ((unsigned int)(d & 127) << 17);
    }
}

// ---- pass B: per bucket, derive per-node offsets locally; writes row_off ----
__global__ __launch_bounds__(256) void k_bucketB(const unsigned int* __restrict__ pairs,
                                                 const int* __restrict__ bucket_base,
                                                 const int* __restrict__ btot,
                                                 int* __restrict__ row_off,
                                                 int* __restrict__ sorted_src) {
    __shared__ int lcnt[128];
    __shared__ int loff[128];
    int b = blockIdx.x, t = threadIdx.x;
    int node0 = b << 7;
    int nn = N_NODES - node0; if (nn > 128) nn = 128;
    int base = bucket_base[b];
    int end  = base + btot[b];
    if (t < 128) lcnt[t] = 0;
    __syncthreads();
    for (int i = base + t; i < end; i += 256) atomicAdd(&lcnt[pairs[i] >> 17], 1);
    __syncthreads();
    if (t < 64) {
        int v0 = lcnt[2 * t], v1 = lcnt[2 * t + 1];
        int s = v0 + v1, ps = s;
        #pragma unroll
        for (int o = 1; o < 64; o <<= 1) { int u = __shfl_up(ps, o); if (t >= o) ps += u; }
        int excl = ps - s;
        loff[2 * t] = excl; loff[2 * t + 1] = excl + v0;
    }
    __syncthreads();
    if (t < nn) row_off[node0 + t] = base + loff[t];
    if (b == NBK - 1 && t == 0) row_off[N_NODES] = end;
    if (t < 128) lcnt[t] = 0;
    __syncthreads();
    for (int i = base + t; i < end; i += 256) {
        unsigned int p = pairs[i];
        int l = p >> 17;
        int pos = atomicAdd(&lcnt[l], 1);
        sorted_src[base + loff[l] + pos] = (int)(p & 0x1FFFFu);
    }
}

// ---- aggregation (R9-proven): persistent grid-stride waves, node-major layout,
// 4x16 subgroups, 16-edge chunks (16 gathers in flight per wave) ----
__global__ __launch_bounds__(256) void k_agg(const uint4* __restrict__ h4,
                                             const int* __restrict__ row_off,
                                             const int* __restrict__ sorted_src,
                                             uint4* __restrict__ agg4) {
    int gw = blockIdx.x * 4 + (threadIdx.x >> 6);   // global wave id
    int lane = threadIdx.x & 63;
    int sub = lane >> 4, li = lane & 15;
    for (int node = gw; node < N_NODES; node += AGG_WAVES) {
        int beg = row_off[node], end = row_off[node + 1];
        float a[8] = {0.f, 0.f, 0.f, 0.f, 0.f, 0.f, 0.f, 0.f};
        for (int base = beg; base < end; base += 16) {
            int sidx[4]; bool val[4];
            #pragma unroll
            for (int u = 0; u < 4; u++) {
                int e = base + 4 * u + sub;
                val[u] = e < end;
                sidx[u] = val[u] ? sorted_src[e] : 0;
            }
            uint4 r[4];
            #pragma unroll
            for (int u = 0; u < 4; u++) {
                if (val[u]) r[u] = h4[(size_t)sidx[u] * 16 + li];
                else        r[u] = make_uint4(0u, 0u, 0u, 0u);
            }
            #pragma unroll
            for (int u = 0; u < 4; u++) {
                acc_pair(r[u].x, a[0], a[1]); acc_pair(r[u].y, a[2], a[3]);
                acc_pair(r[u].z, a[4], a[5]); acc_pair(r[u].w, a[6], a[7]);
            }
        }
        #pragma unroll
        for (int i = 0; i < 8; i++) {
            a[i] += __shfl_xor(a[i], 16);
            a[i] += __shfl_xor(a[i], 32);
        }
        if (sub == 0) {
            uint4 o;
            o.x = f2bf(a[0]) | (f2bf(a[1]) << 16);
            o.y = f2bf(a[2]) | (f2bf(a[3]) << 16);
            o.z = f2bf(a[4]) | (f2bf(a[5]) << 16);
            o.w = f2bf(a[6]) | (f2bf(a[7]) << 16);
            agg4[(size_t)node * 16 + li] = o;
        }
    }
}

// ---- fused GraphConv GEMM, LDS-free K-loop, 128x128 tile, 512-thread blocks ----
// 8 waves per block, each a 32-row x 64-col quadrant: acc 32 VGPR/wave ->
// ~16-24 waves/CU (vs 12 at 4-wave blocks) without R10's B-duplication.
__global__ __launch_bounds__(512) void k_gemm(const unsigned short* __restrict__ Ag,
                                              const unsigned short* __restrict__ H,
                                              const unsigned short* __restrict__ Wt,
                                              const float* __restrict__ bias,
                                              unsigned short* __restrict__ Hout) {
    __shared__ unsigned short Es[64 * 144];  // 18.4 KB epilogue staging only
    int tid = threadIdx.x;
    int lane = tid & 63, wid = tid >> 6;     // 8 waves
    int wr = (wid >> 1) * 32, wc = (wid & 1) * 64;
    int row0 = blockIdx.x * 128;
    f32x4 acc[2][4] = {};

    int ksub = (lane >> 4) * 8;
    const unsigned short* Aga = Ag + (size_t)(row0 + wr + (lane & 15)) * 128 + ksub;
    const unsigned short* Ha  = H  + (size_t)(row0 + wr + (lane & 15)) * 128 + ksub;
    const unsigned short* Bb  = Wt + (size_t)(wc + (lane & 15)) * 256 + ksub;

    auto load_frags = [&](short8* a, short8* b, int s) {
        const unsigned short* ab = (s < 4 ? Aga : Ha) + (s & 3) * 32;
        #pragma unroll
        for (int mi = 0; mi < 2; mi++) a[mi] = *(const short8*)(ab + mi * 16 * 128);
        const unsigned short* bp = Bb + s * 32;
        #pragma unroll
        for (int ni = 0; ni < 4; ni++) b[ni] = *(const short8*)(bp + ni * 16 * 256);
    };
    auto do_mfma = [&](short8* a, short8* b) {
        #pragma unroll
        for (int mi = 0; mi < 2; mi++)
            #pragma unroll
            for (int ni = 0; ni < 4; ni++)
                acc[mi][ni] = __builtin_amdgcn_mfma_f32_16x16x32_bf16(a[mi], b[ni], acc[mi][ni], 0, 0, 0);
    };

    short8 a0[2], b0[4], a1[2], b1[4];
    load_frags(a0, b0, 0);
    #pragma unroll
    for (int s = 0; s < 8; s += 2) {
        load_frags(a1, b1, s + 1);
        do_mfma(a0, b0);
        if (s + 2 < 8) load_frags(a0, b0, s + 2);
        do_mfma(a1, b1);
    }

    // epilogue: C/D map col=lane&15, row=(lane>>4)*4+reg (m89-verified).
    // Two 64-row passes; pass p staged by the 4 waves with (wid>>2)==p.
    int cb = wc + (lane & 15);
    int rs = (lane >> 4) * 4;
    #pragma unroll
    for (int p = 0; p < 2; ++p) {
        __syncthreads();
        if ((wid >> 2) == p) {
            #pragma unroll
            for (int ni = 0; ni < 4; ni++) {
                int col = cb + ni * 16;
                float bn = bias[col];
                #pragma unroll
                for (int mi = 0; mi < 2; mi++) {
                    int rloc = (wr & 63) + mi * 16 + rs;
                    #pragma unroll
                    for (int rr = 0; rr < 4; rr++) {
                        float v = acc[mi][ni][rr] + bn;
                        v = v > 0.f ? v : 0.f;
                        Es[(rloc + rr) * 144 + col] = (unsigned short)f2bf(v);
                    }
                }
            }
        }
        __syncthreads();
        int rloc = tid >> 3;                  // 0..63
        int c4 = (tid & 7) * 2;               // uint4 chunk base (16 chunks/row)
        uint4* gd = (uint4*)(Hout + (size_t)(row0 + 64 * p + rloc) * 128);
        const uint4* es = (const uint4*)(Es + (size_t)rloc * 144);
        #pragma unroll
        for (int j = 0; j < 2; j++) gd[c4 + j] = es[c4 + j];
    }
}

// ---- pooling: batch is sorted; per-block local accumulate ----
__global__ __launch_bounds__(128) void k_pool(const unsigned short* __restrict__ h,
                                              const int* __restrict__ batch,
                                              float* __restrict__ pooled, int* __restrict__ counts) {
    __shared__ int bsh[128];
    int start = blockIdx.x * 128, t = threadIdx.x;
    int end = start + 128; if (end > N_NODES) end = N_NODES;
    int nn = end - start;
    if (t < nn) bsh[t] = batch[start + t];
    __syncthreads();
    float acc = 0.f; int cur = -1, cnt = 0;
    for (int i = 0; i < nn; i++) {
        int g = bsh[i];
        if (g != cur) {
            if (cur >= 0) { atomicAdd(&pooled[cur * 128 + t], acc); if (t == 0) atomicAdd(&counts[cur], cnt); }
            cur = g; acc = 0.f; cnt = 0;
        }
        acc += bf2f(h[(size_t)(start + i) * 128 + t]);
        cnt++;
    }
    if (cur >= 0) { atomicAdd(&pooled[cur * 128 + t], acc); if (t == 0) atomicAdd(&counts[cur], cnt); }
}

// ---- SNN layer 1: snn_h = relu(x @ w1 + b1), fp32 vector ----
__global__ __launch_bounds__(256) void k_snn1(const float* __restrict__ x, const float* __restrict__ w1,
                                              const float* __restrict__ b1, float* __restrict__ out) {
    __shared__ float xs[SNN_IN];
    int m = blockIdx.x, tid = threadIdx.x;
    for (int i = tid; i < SNN_IN; i += 256) xs[i] = x[m * SNN_IN + i];
    __syncthreads();
    float a0 = 0.f, a1 = 0.f, a2 = 0.f, a3 = 0.f;
    for (int k = 0; k < SNN_IN; k++) {
        float xv = xs[k];
        const float* wr = w1 + (size_t)k * SNN_HID + tid;
        a0 += xv * wr[0]; a1 += xv * wr[256]; a2 += xv * wr[512]; a3 += xv * wr[768];
    }
    float v;
    v = a0 + b1[tid];       out[m * SNN_HID + tid]       = v > 0.f ? v : 0.f;
    v = a1 + b1[tid + 256]; out[m * SNN_HID + tid + 256] = v > 0.f ? v : 0.f;
    v = a2 + b1[tid + 512]; out[m * SNN_HID + tid + 512] = v > 0.f ? v : 0.f;
    v = a3 + b1[tid + 768]; out[m * SNN_HID + tid + 768] = v > 0.f ? v : 0.f;
}

// ---- head: gnn logits + snn logits + fusion, one wave per graph ----
__global__ __launch_bounds__(64) void k_head(const float* __restrict__ pooled, const int* __restrict__ counts,
                                             const float* __restrict__ lin_w, const float* __restrict__ lin_b,
                                             const float* __restrict__ snn_h, const float* __restrict__ w2,
                                             const float* __restrict__ b2, const float* __restrict__ fuse_w,
                                             const float* __restrict__ fuse_b, float* __restrict__ out) {
    int m = blockIdx.x, lane = threadIdx.x;
    __shared__ float sm[20];
    float cnt = (float)(counts[m] > 0 ? counts[m] : 1);
    float p0 = pooled[m * 128 + lane] / cnt;
    float p1 = pooled[m * 128 + 64 + lane] / cnt;
    for (int c = 0; c < NCLS; c++) {
        float v = p0 * lin_w[lane * 10 + c] + p1 * lin_w[(lane + 64) * 10 + c];
        #pragma unroll
        for (int o = 32; o > 0; o >>= 1) v += __shfl_down(v, o);
        if (lane == 0) sm[10 + c] = v + lin_b[c];
    }
    for (int c = 0; c < NCLS; c++) {
        float v = 0.f;
        #pragma unroll
        for (int j = 0; j < 16; j++) {
            int k = lane + j * 64;
            v += snn_h[m * SNN_HID + k] * w2[k * 10 + c];
        }
        #pragma unroll
        for (int o = 32; o > 0; o >>= 1) v += __shfl_down(v, o);
        if (lane == 0) sm[c] = 0.85f * (v + b2[c]);
    }
    __syncthreads();
    if (lane < NCLS) {
        float o = fuse_b[lane];
        #pragma unroll
        for (int j = 0; j < 20; j++) o += sm[j] * fuse_w[j * 10 + lane];
        out[m * 10 + lane] = o;
    }
}

extern "C" void kernel_launch(void* const* d_in, const int* in_sizes, int n_in,
                              void* d_out, int out_size, void* d_ws, size_t ws_size,
                              hipStream_t stream) {
    const float* snn_x  = (const float*)d_in[0];
    const float* x      = (const float*)d_in[1];
    const int*   ei     = (const int*)d_in[2];
    const int*   batch  = (const int*)d_in[3];
    const float* w1     = (const float*)d_in[4];
    const float* b1     = (const float*)d_in[5];
    const float* w2     = (const float*)d_in[6];
    const float* b2     = (const float*)d_in[7];
    const float* wrel   = (const float*)d_in[8];
    const float* wroot  = (const float*)d_in[9];
    const float* brel   = (const float*)d_in[10];
    const float* lin_w  = (const float*)d_in[11];
    const float* lin_b  = (const float*)d_in[12];
    const float* fuse_w = (const float*)d_in[13];
    const float* fuse_b = (const float*)d_in[14];
    const int* srcv = ei;
    const int* dstv = ei + N_EDGES;

    char* ws = (char*)d_ws;
    size_t off = 0;
    auto alloc = [&](size_t b) { char* p = ws + off; off = (off + b + 255) & ~(size_t)255; return p; };
    unsigned short* h0   = (unsigned short*)alloc((size_t)M_PAD * 128 * 2);   // 25.6 MB
    unsigned short* h1   = (unsigned short*)alloc((size_t)M_PAD * 128 * 2);   // 25.6 MB
    unsigned short* agg  = (unsigned short*)alloc((size_t)M_PAD * 128 * 2);   // 25.6 MB
    unsigned short* Wt   = (unsigned short*)alloc((size_t)N_LAYERS * 128 * 256 * 2);
    int* sorted_src = (int*)alloc((size_t)N_EDGES * 4);
    unsigned int* pairs = (unsigned int*)alloc((size_t)N_EDGES * 4);
    int* chunk_hist = (int*)alloc((size_t)SORT_NCH * NBK * 4);   // 1.22 MB
    int* row_off    = (int*)alloc((size_t)(N_NODES + 1) * 4);
    int* btot       = (int*)alloc((size_t)NBK * 4);
    int* bucket_base= (int*)alloc((size_t)NBK * 4);
    float* pooled   = (float*)alloc((size_t)N_GRAPHS * 128 * 4);
    int* counts     = (int*)alloc((size_t)N_GRAPHS * 4);
    float* snn_h    = (float*)alloc((size_t)N_GRAPHS * SNN_HID * 4);

    hipMemsetAsync(pooled, 0, (size_t)N_GRAPHS * 128 * 4, stream);
    hipMemsetAsync(counts, 0, (size_t)N_GRAPHS * 4, stream);

    k_histA<<<SORT_NCH, 256, 0, stream>>>(dstv, chunk_hist);
    k_colscan<<<NBK, 64, 0, stream>>>(chunk_hist, btot);
    k_bscan<<<1, 256, 0, stream>>>(btot, bucket_base);
    k_scatterA<<<SORT_NCH, 256, 0, stream>>>(srcv, dstv, chunk_hist, bucket_base, pairs);
    k_bucketB<<<NBK, 256, 0, stream>>>(pairs, bucket_base, btot, row_off, sorted_src);
    k_convert<<<(XPAIRS + WELEMS + 255) / 256, 256, 0, stream>>>(x, wrel, wroot, (unsigned int*)h0, Wt);

    unsigned short* hc = h0;
    unsigned short* hn = h1;
    for (int l = 0; l < N_LAYERS; l++) {
        k_agg<<<AGG_BLOCKS, 256, 0, stream>>>((const uint4*)hc, row_off, sorted_src, (uint4*)agg);
        k_gemm<<<MBLK, 512, 0, stream>>>(agg, hc, Wt + (size_t)l * 128 * 256, brel + l * 128, hn);
        unsigned short* t = hc; hc = hn; hn = t;
    }
    k_pool<<<(N_NODES + 127) / 128, 128, 0, stream>>>(hc, batch, pooled, counts);
    k_snn1<<<N_GRAPHS, 256, 0, stream>>>(snn_x, w1, b1, snn_h);
    k_head<<<N_GRAPHS, 64, 0, stream>>>(pooled, counts, lin_w, lin_b, snn_h, w2, b2, fuse_w, fuse_b,
                                        (float*)d_out);
}

// Round 13
// 932.723 us; speedup vs baseline: 3.1890x; 1.1058x over previous
//
#include <hip/hip_runtime.h>
#include <hip/hip_bf16.h>

#define N_NODES 100000
#define N_EDGES 1600000
#define DIM     128
#define N_LAYERS 7
#define N_GRAPHS 64
#define SNN_IN  512
#define SNN_HID 1024
#define NCLS    10
#define M_PAD   100096   // 782 * 128
#define MBLK    782
#define NBK     782      // buckets of 128 nodes
#define SORT_CHUNK 4096
#define SORT_NCH   391   // ceil(1600000/4096)
#define XPAIRS  (N_NODES * 64)
#define WELEMS  (N_LAYERS * DIM * 256)
#define AGG_BLOCKS 2048
#define AGG_WAVES  (AGG_BLOCKS * 4)
#define POOL_NB 782      // ceil(100000/128)

typedef __attribute__((ext_vector_type(8))) short short8;
typedef __attribute__((ext_vector_type(4))) float f32x4;

__device__ __forceinline__ unsigned int f2bf(float f) {
    unsigned int u = __float_as_uint(f);
    return (u + 0x7fffu + ((u >> 16) & 1u)) >> 16;   // RNE
}
__device__ __forceinline__ float bf2f(unsigned short b) {
    return __uint_as_float(((unsigned int)b) << 16);
}
__device__ __forceinline__ void acc_pair(unsigned int u, float& lo, float& hi) {
    lo += __uint_as_float(u << 16);
    hi += __uint_as_float(u & 0xffff0000u);
}

// ---- setup: fp32 x -> bf16 h0 pairs (node-major), W -> Wt[l][n][k] bf16.
// Also zero-inits pooled/counts (replaces 2 memset dispatches). ----
__global__ void k_convert(const float* __restrict__ x, const float* __restrict__ wrel,
                          const float* __restrict__ wroot, unsigned int* __restrict__ h,
                          unsigned short* __restrict__ Wt,
                          float* __restrict__ pooled, int* __restrict__ counts) {
    int i = blockIdx.x * blockDim.x + threadIdx.x;
    if (i < N_GRAPHS * 128) pooled[i] = 0.f;
    if (i >= N_GRAPHS * 128 && i < N_GRAPHS * 129) counts[i - N_GRAPHS * 128] = 0;
    if (i < XPAIRS) {
        float2 v = ((const float2*)x)[i];
        h[i] = f2bf(v.x) | (f2bf(v.y) << 16);
    } else {
        int idx = i - XPAIRS;
        if (idx < WELEMS) {
            int l = idx >> 15, rem = idx & 32767, n = rem >> 8, k = rem & 255;
            float v = (k < 128) ? wrel[l * 16384 + k * 128 + n]
                                : wroot[l * 16384 + (k - 128) * 128 + n];
            Wt[idx] = (unsigned short)f2bf(v);
        }
    }
}

// ---- sort pass A1: per-chunk LDS histogram over 782 buckets (no global atomics) ----
__global__ __launch_bounds__(256) void k_histA(const int* __restrict__ dst,
                                               int* __restrict__ chunk_hist) {
    __shared__ int hist[NBK];
    int b = blockIdx.x, t = threadIdx.x;
    int e0 = b * SORT_CHUNK;
    int e1 = e0 + SORT_CHUNK; if (e1 > N_EDGES) e1 = N_EDGES;
    for (int i = t; i < NBK; i += 256) hist[i] = 0;
    __syncthreads();
    for (int e = e0 + t; e < e1; e += 256) atomicAdd(&hist[dst[e] >> 7], 1);
    __syncthreads();
    for (int i = t; i < NBK; i += 256) chunk_hist[b * NBK + i] = hist[i];
}

// ---- sort pass A2: per-bucket exclusive prefix over the 391 chunk counts ----
__global__ __launch_bounds__(64) void k_colscan(int* __restrict__ chunk_hist,
                                                int* __restrict__ btot) {
    int b = blockIdx.x;
    int lane = threadIdx.x;
    const int C = (SORT_NCH + 63) / 64;   // 7
    int vals[C]; int sum = 0;
    #pragma unroll
    for (int j = 0; j < C; j++) {
        int c = lane * C + j;
        vals[j] = (c < SORT_NCH) ? chunk_hist[c * NBK + b] : 0;
        sum += vals[j];
    }
    int s = sum;
    #pragma unroll
    for (int o = 1; o < 64; o <<= 1) { int t = __shfl_up(s, o); if (lane >= o) s += t; }
    if (lane == 63) btot[b] = s;
    int run = s - sum;
    #pragma unroll
    for (int j = 0; j < C; j++) {
        int c = lane * C + j;
        if (c < SORT_NCH) chunk_hist[c * NBK + b] = run;
        run += vals[j];
    }
}

// ---- tiny cross-bucket scan ----
__global__ __launch_bounds__(256) void k_bscan(const int* __restrict__ btot,
                                               int* __restrict__ bucket_base) {
    __shared__ int wsum[4];
    int tid = threadIdx.x, lane = tid & 63, wid = tid >> 6;
    int i0 = tid * 4;
    int v[4]; int sum = 0;
    #pragma unroll
    for (int j = 0; j < 4; j++) { int i = i0 + j; v[j] = (i < NBK) ? btot[i] : 0; sum += v[j]; }
    int s = sum;
    #pragma unroll
    for (int o = 1; o < 64; o <<= 1) { int t = __shfl_up(s, o); if (lane >= o) s += t; }
    if (lane == 63) wsum[wid] = s;
    __syncthreads();
    if (tid == 0) {
        int acc = 0;
        #pragma unroll
        for (int w = 0; w < 4; w++) { acc += wsum[w]; wsum[w] = acc; }
    }
    __syncthreads();
    int prefix = s - sum + (wid ? wsum[wid - 1] : 0);
    #pragma unroll
    for (int j = 0; j < 4; j++) { int i = i0 + j; if (i < NBK) bucket_base[i] = prefix; prefix += v[j]; }
}

// ---- sort pass A3: scatter via LDS cursors ----
__global__ __launch_bounds__(256) void k_scatterA(const int* __restrict__ src,
                                                  const int* __restrict__ dst,
                                                  const int* __restrict__ chunk_hist,
                                                  const int* __restrict__ bucket_base,
                                                  unsigned int* __restrict__ pairs) {
    __shared__ int lcur[NBK];
    int b = blockIdx.x, t = threadIdx.x;
    int e0 = b * SORT_CHUNK;
    int e1 = e0 + SORT_CHUNK; if (e1 > N_EDGES) e1 = N_EDGES;
    for (int i = t; i < NBK; i += 256) lcur[i] = chunk_hist[b * NBK + i] + bucket_base[i];
    __syncthreads();
    for (int e = e0 + t; e < e1; e += 256) {
        int d = dst[e];
        int bk = d >> 7;
        int pos = atomicAdd(&lcur[bk], 1);
        pairs[pos] = (unsigned int)src[e] | ((unsigned int)(d & 127) << 17);
    }
}

// ---- pass B: per bucket, derive per-node offsets locally; writes row_off ----
__global__ __launch_bounds__(256) void k_bucketB(const unsigned int* __restrict__ pairs,
                                                 const int* __restrict__ bucket_base,
                                                 const int* __restrict__ btot,
                                                 int* __restrict__ row_off,
                                                 int* __restrict__ sorted_src) {
    __shared__ int lcnt[128];
    __shared__ int loff[128];
    int b = blockIdx.x, t = threadIdx.x;
    int node0 = b << 7;
    int nn = N_NODES - node0; if (nn > 128) nn = 128;
    int base = bucket_base[b];
    int end  = base + btot[b];
    if (t < 128) lcnt[t] = 0;
    __syncthreads();
    for (int i = base + t; i < end; i += 256) atomicAdd(&lcnt[pairs[i] >> 17], 1);
    __syncthreads();
    if (t < 64) {
        int v0 = lcnt[2 * t], v1 = lcnt[2 * t + 1];
        int s = v0 + v1, ps = s;
        #pragma unroll
        for (int o = 1; o < 64; o <<= 1) { int u = __shfl_up(ps, o); if (t >= o) ps += u; }
        int excl = ps - s;
        loff[2 * t] = excl; loff[2 * t + 1] = excl + v0;
    }
    __syncthreads();
    if (t < nn) row_off[node0 + t] = base + loff[t];
    if (b == NBK - 1 && t == 0) row_off[N_NODES] = end;
    if (t < 128) lcnt[t] = 0;
    __syncthreads();
    for (int i = base + t; i < end; i += 256) {
        unsigned int p = pairs[i];
        int l = p >> 17;
        int pos = atomicAdd(&lcnt[l], 1);
        sorted_src[base + loff[l] + pos] = (int)(p & 0x1FFFFu);
    }
}

// ---- aggregation (R9-proven): persistent grid-stride waves, node-major layout,
// 4x16 subgroups, 16-edge chunks (16 gathers in flight per wave) ----
__global__ __launch_bounds__(256) void k_agg(const uint4* __restrict__ h4,
                                             const int* __restrict__ row_off,
                                             const int* __restrict__ sorted_src,
                                             uint4* __restrict__ agg4) {
    int gw = blockIdx.x * 4 + (threadIdx.x >> 6);   // global wave id
    int lane = threadIdx.x & 63;
    int sub = lane >> 4, li = lane & 15;
    for (int node = gw; node < N_NODES; node += AGG_WAVES) {
        int beg = row_off[node], end = row_off[node + 1];
        float a[8] = {0.f, 0.f, 0.f, 0.f, 0.f, 0.f, 0.f, 0.f};
        for (int base = beg; base < end; base += 16) {
            int sidx[4]; bool val[4];
            #pragma unroll
            for (int u = 0; u < 4; u++) {
                int e = base + 4 * u + sub;
                val[u] = e < end;
                sidx[u] = val[u] ? sorted_src[e] : 0;
            }
            uint4 r[4];
            #pragma unroll
            for (int u = 0; u < 4; u++) {
                if (val[u]) r[u] = h4[(size_t)sidx[u] * 16 + li];
                else        r[u] = make_uint4(0u, 0u, 0u, 0u);
            }
            #pragma unroll
            for (int u = 0; u < 4; u++) {
                acc_pair(r[u].x, a[0], a[1]); acc_pair(r[u].y, a[2], a[3]);
                acc_pair(r[u].z, a[4], a[5]); acc_pair(r[u].w, a[6], a[7]);
            }
        }
        #pragma unroll
        for (int i = 0; i < 8; i++) {
            a[i] += __shfl_xor(a[i], 16);
            a[i] += __shfl_xor(a[i], 32);
        }
        if (sub == 0) {
            uint4 o;
            o.x = f2bf(a[0]) | (f2bf(a[1]) << 16);
            o.y = f2bf(a[2]) | (f2bf(a[3]) << 16);
            o.z = f2bf(a[4]) | (f2bf(a[5]) << 16);
            o.w = f2bf(a[6]) | (f2bf(a[7]) << 16);
            agg4[(size_t)node * 16 + li] = o;
        }
    }
}

// ---- fused GraphConv GEMM, LDS-free K-loop (exact R9 config: 782x256, 128x128
// tile, 4 waves of 64x64, acc[4][4]). R10/R12 geometry changes both regressed. ----
__global__ __launch_bounds__(256) void k_gemm(const unsigned short* __restrict__ Ag,
                                              const unsigned short* __restrict__ H,
                                              const unsigned short* __restrict__ Wt,
                                              const float* __restrict__ bias,
                                              unsigned short* __restrict__ Hout) {
    __shared__ unsigned short Es[64 * 144];  // 18.4 KB epilogue staging only
    int tid = threadIdx.x;
    int lane = tid & 63, wid = tid >> 6;
    int wr = (wid >> 1) * 64, wc = (wid & 1) * 64;
    int row0 = blockIdx.x * 128;
    f32x4 acc[4][4] = {};

    int ksub = (lane >> 4) * 8;
    const unsigned short* Aga = Ag + (size_t)(row0 + wr + (lane & 15)) * 128 + ksub;
    const unsigned short* Ha  = H  + (size_t)(row0 + wr + (lane & 15)) * 128 + ksub;
    const unsigned short* Bb  = Wt + (size_t)(wc + (lane & 15)) * 256 + ksub;

    auto load_frags = [&](short8* a, short8* b, int s) {
        const unsigned short* ab = (s < 4 ? Aga : Ha) + (s & 3) * 32;
        #pragma unroll
        for (int mi = 0; mi < 4; mi++) a[mi] = *(const short8*)(ab + mi * 16 * 128);
        const unsigned short* bp = Bb + s * 32;
        #pragma unroll
        for (int ni = 0; ni < 4; ni++) b[ni] = *(const short8*)(bp + ni * 16 * 256);
    };
    auto do_mfma = [&](short8* a, short8* b) {
        #pragma unroll
        for (int mi = 0; mi < 4; mi++)
            #pragma unroll
            for (int ni = 0; ni < 4; ni++)
                acc[mi][ni] = __builtin_amdgcn_mfma_f32_16x16x32_bf16(a[mi], b[ni], acc[mi][ni], 0, 0, 0);
    };

    short8 a0[4], b0[4], a1[4], b1[4];
    load_frags(a0, b0, 0);
    #pragma unroll
    for (int s = 0; s < 8; s += 2) {
        load_frags(a1, b1, s + 1);
        do_mfma(a0, b0);
        if (s + 2 < 8) load_frags(a0, b0, s + 2);
        do_mfma(a1, b1);
    }

    // epilogue: C/D map col=lane&15, row=(lane>>4)*4+reg (m89-verified)
    int cb = wc + (lane & 15);
    int rs = (lane >> 4) * 4;
    #pragma unroll
    for (int p = 0; p < 2; ++p) {
        __syncthreads();
        if (wr == 64 * p) {
            #pragma unroll
            for (int ni = 0; ni < 4; ni++) {
                int col = cb + ni * 16;
                float bn = bias[col];
                #pragma unroll
                for (int mi = 0; mi < 4; mi++) {
                    int rloc = mi * 16 + rs;
                    #pragma unroll
                    for (int rr = 0; rr < 4; rr++) {
                        float v = acc[mi][ni][rr] + bn;
                        v = v > 0.f ? v : 0.f;
                        Es[(rloc + rr) * 144 + col] = (unsigned short)f2bf(v);
                    }
                }
            }
        }
        __syncthreads();
        int rloc = tid >> 2;                  // 0..63
        int c4 = (tid & 3) * 4;               // uint4 chunk base (16 chunks/row)
        uint4* gd = (uint4*)(Hout + (size_t)(row0 + 64 * p + rloc) * 128);
        const uint4* es = (const uint4*)(Es + (size_t)rloc * 144);
        #pragma unroll
        for (int j = 0; j < 4; j++) gd[c4 + j] = es[c4 + j];
    }
}

// ---- pooling + SNN layer 1 merged (independent work, block-role split):
// blocks 0..781 pool 128 nodes each; blocks 782..845 are one graph's snn1 ----
__global__ __launch_bounds__(256) void k_pool_snn(const unsigned short* __restrict__ h,
                                                  const int* __restrict__ batch,
                                                  float* __restrict__ pooled,
                                                  int* __restrict__ counts,
                                                  const float* __restrict__ x,
                                                  const float* __restrict__ w1,
                                                  const float* __restrict__ b1,
                                                  float* __restrict__ snn_out) {
    if (blockIdx.x < POOL_NB) {
        __shared__ int bsh[128];
        int start = blockIdx.x * 128;
        int t = threadIdx.x & 127;
        int half = threadIdx.x >> 7;          // 2 threads per dim? no: split rows
        // 256 threads: thread t<128 handles dim t for rows [start, start+128)
        if (half == 0) {
            int end = start + 128; if (end > N_NODES) end = N_NODES;
            int nn = end - start;
            if (t < nn) bsh[t] = batch[start + t];
        }
        __syncthreads();
        if (half == 1) {
            int end = start + 128; if (end > N_NODES) end = N_NODES;
            int nn = end - start;
            float acc = 0.f; int cur = -1, cnt = 0;
            for (int i = 0; i < nn; i++) {
                int g = bsh[i];
                if (g != cur) {
                    if (cur >= 0) { atomicAdd(&pooled[cur * 128 + t], acc); if (t == 0) atomicAdd(&counts[cur], cnt); }
                    cur = g; acc = 0.f; cnt = 0;
                }
                acc += bf2f(h[(size_t)(start + i) * 128 + t]);
                cnt++;
            }
            if (cur >= 0) { atomicAdd(&pooled[cur * 128 + t], acc); if (t == 0) atomicAdd(&counts[cur], cnt); }
        } else {
            int end = start + 128; if (end > N_NODES) end = N_NODES;
            int nn = end - start;
            float acc = 0.f; int cur = -1;
            int td = t + 0;                    // dims 0..127 handled by half==1 above;
            // half==0 handles dims via second accumulator pass over same dims?
            // Split dims instead: half 0 -> even store path not needed. Do nothing.
            (void)nn; (void)acc; (void)cur; (void)td;
        }
    } else {
        int m = blockIdx.x - POOL_NB;
        __shared__ float xs[SNN_IN];
        int tid = threadIdx.x;
        for (int i = tid; i < SNN_IN; i += 256) xs[i] = x[m * SNN_IN + i];
        __syncthreads();
        float a0 = 0.f, a1 = 0.f, a2 = 0.f, a3 = 0.f;
        for (int k = 0; k < SNN_IN; k++) {
            float xv = xs[k];
            const float* wr = w1 + (size_t)k * SNN_HID + tid;
            a0 += xv * wr[0]; a1 += xv * wr[256]; a2 += xv * wr[512]; a3 += xv * wr[768];
        }
        float v;
        v = a0 + b1[tid];       snn_out[m * SNN_HID + tid]       = v > 0.f ? v : 0.f;
        v = a1 + b1[tid + 256]; snn_out[m * SNN_HID + tid + 256] = v > 0.f ? v : 0.f;
        v = a2 + b1[tid + 512]; snn_out[m * SNN_HID + tid + 512] = v > 0.f ? v : 0.f;
        v = a3 + b1[tid + 768]; snn_out[m * SNN_HID + tid + 768] = v > 0.f ? v : 0.f;
    }
}

// ---- head: gnn logits + snn logits + fusion, one wave per graph ----
__global__ __launch_bounds__(64) void k_head(const float* __restrict__ pooled, const int* __restrict__ counts,
                                             const float* __restrict__ lin_w, const float* __restrict__ lin_b,
                                             const float* __restrict__ snn_h, const float* __restrict__ w2,
                                             const float* __restrict__ b2, const float* __restrict__ fuse_w,
                                             const float* __restrict__ fuse_b, float* __restrict__ out) {
    int m = blockIdx.x, lane = threadIdx.x;
    __shared__ float sm[20];
    float cnt = (float)(counts[m] > 0 ? counts[m] : 1);
    float p0 = pooled[m * 128 + lane] / cnt;
    float p1 = pooled[m * 128 + 64 + lane] / cnt;
    for (int c = 0; c < NCLS; c++) {
        float v = p0 * lin_w[lane * 10 + c] + p1 * lin_w[(lane + 64) * 10 + c];
        #pragma unroll
        for (int o = 32; o > 0; o >>= 1) v += __shfl_down(v, o);
        if (lane == 0) sm[10 + c] = v + lin_b[c];
    }
    for (int c = 0; c < NCLS; c++) {
        float v = 0.f;
        #pragma unroll
        for (int j = 0; j < 16; j++) {
            int k = lane + j * 64;
            v += snn_h[m * SNN_HID + k] * w2[k * 10 + c];
        }
        #pragma unroll
        for (int o = 32; o > 0; o >>= 1) v += __shfl_down(v, o);
        if (lane == 0) sm[c] = 0.85f * (v + b2[c]);
    }
    __syncthreads();
    if (lane < NCLS) {
        float o = fuse_b[lane];
        #pragma unroll
        for (int j = 0; j < 20; j++) o += sm[j] * fuse_w[j * 10 + lane];
        out[m * 10 + lane] = o;
    }
}

extern "C" void kernel_launch(void* const* d_in, const int* in_sizes, int n_in,
                              void* d_out, int out_size, void* d_ws, size_t ws_size,
                              hipStream_t stream) {
    const float* snn_x  = (const float*)d_in[0];
    const float* x      = (const float*)d_in[1];
    const int*   ei     = (const int*)d_in[2];
    const int*   batch  = (const int*)d_in[3];
    const float* w1     = (const float*)d_in[4];
    const float* b1     = (const float*)d_in[5];
    const float* w2     = (const float*)d_in[6];
    const float* b2     = (const float*)d_in[7];
    const float* wrel   = (const float*)d_in[8];
    const float* wroot  = (const float*)d_in[9];
    const float* brel   = (const float*)d_in[10];
    const float* lin_w  = (const float*)d_in[11];
    const float* lin_b  = (const float*)d_in[12];
    const float* fuse_w = (const float*)d_in[13];
    const float* fuse_b = (const float*)d_in[14];
    const int* srcv = ei;
    const int* dstv = ei + N_EDGES;

    char* ws = (char*)d_ws;
    size_t off = 0;
    auto alloc = [&](size_t b) { char* p = ws + off; off = (off + b + 255) & ~(size_t)255; return p; };
    unsigned short* h0   = (unsigned short*)alloc((size_t)M_PAD * 128 * 2);   // 25.6 MB
    unsigned short* h1   = (unsigned short*)alloc((size_t)M_PAD * 128 * 2);   // 25.6 MB
    unsigned short* agg  = (unsigned short*)alloc((size_t)M_PAD * 128 * 2);   // 25.6 MB
    unsigned short* Wt   = (unsigned short*)alloc((size_t)N_LAYERS * 128 * 256 * 2);
    int* sorted_src = (int*)alloc((size_t)N_EDGES * 4);
    unsigned int* pairs = (unsigned int*)alloc((size_t)N_EDGES * 4);
    int* chunk_hist = (int*)alloc((size_t)SORT_NCH * NBK * 4);   // 1.22 MB
    int* row_off    = (int*)alloc((size_t)(N_NODES + 1) * 4);
    int* btot       = (int*)alloc((size_t)NBK * 4);
    int* bucket_base= (int*)alloc((size_t)NBK * 4);
    float* pooled   = (float*)alloc((size_t)N_GRAPHS * 128 * 4);
    int* counts     = (int*)alloc((size_t)N_GRAPHS * 4);
    float* snn_h    = (float*)alloc((size_t)N_GRAPHS * SNN_HID * 4);

    k_histA<<<SORT_NCH, 256, 0, stream>>>(dstv, chunk_hist);
    k_colscan<<<NBK, 64, 0, stream>>>(chunk_hist, btot);
    k_bscan<<<1, 256, 0, stream>>>(btot, bucket_base);
    k_scatterA<<<SORT_NCH, 256, 0, stream>>>(srcv, dstv, chunk_hist, bucket_base, pairs);
    k_bucketB<<<NBK, 256, 0, stream>>>(pairs, bucket_base, btot, row_off, sorted_src);
    k_convert<<<(XPAIRS + WELEMS + 255) / 256, 256, 0, stream>>>(x, wrel, wroot, (unsigned int*)h0,
                                                                 Wt, pooled, counts);

    unsigned short* hc = h0;
    unsigned short* hn = h1;
    for (int l = 0; l < N_LAYERS; l++) {
        k_agg<<<AGG_BLOCKS, 256, 0, stream>>>((const uint4*)hc, row_off, sorted_src, (uint4*)agg);
        k_gemm<<<MBLK, 256, 0, stream>>>(agg, hc, Wt + (size_t)l * 128 * 256, brel + l * 128, hn);
        unsigned short* t = hc; hc = hn; hn = t;
    }
    k_pool_snn<<<POOL_NB + N_GRAPHS, 256, 0, stream>>>(hc, batch, pooled, counts,
                                                       snn_x, w1, b1, snn_h);
    k_head<<<N_GRAPHS, 64, 0, stream>>>(pooled, counts, lin_w, lin_b, snn_h, w2, b2, fuse_w, fuse_b,
                                        (float*)d_out);
}